// Round 7
// baseline (208.426 us; speedup 1.0000x reference)
//
#include <hip/hip_runtime.h>

typedef unsigned short u16;
typedef unsigned int   u32;
using short8 = __attribute__((ext_vector_type(8))) short;
using f32x4  = __attribute__((ext_vector_type(4))) float;
using f32x16 = __attribute__((ext_vector_type(16))) float;
using u32x4  = __attribute__((ext_vector_type(4))) unsigned int;

#define S_LEN 4096
#define EMB   768
#define NH    12
#define DH    64

// 0.125 (=1/sqrt(64)) * log2(e): folded into Q so softmax uses exp2 directly
#define QSCALE 0.18033688011112042f

__device__ __forceinline__ u16 f2bf(float f) {
  unsigned int u = __builtin_bit_cast(unsigned int, f);
  u += 0x7fffu + ((u >> 16) & 1u);
  return (u16)(u >> 16);
}

__device__ __forceinline__ u32 cvtpk(float lo, float hi) {
  u32 r;
  asm("v_cvt_pk_bf16_f32 %0, %1, %2" : "=v"(r) : "v"(lo), "v"(hi));
  return r;
}

// Cross-half (lane ^ 32) combines -- PROVEN primitive (R3/R6 passed).
// Raw v_permlane32_swap asm failed both orientations (R4/R5); do not use.
__device__ __forceinline__ float pr_max(float v) {
  return fmaxf(v, __shfl_xor(v, 32));
}
__device__ __forceinline__ float pr_add(float v) {
  return v + __shfl_xor(v, 32);
}

__device__ __forceinline__ float fexp2(float x) {
#if __has_builtin(__builtin_amdgcn_exp2f)
  return __builtin_amdgcn_exp2f(x);
#else
  return exp2f(x);
#endif
}

__device__ __forceinline__ f32x4 mfma16(short8 a, short8 b, f32x4 c) {
  return __builtin_amdgcn_mfma_f32_16x16x32_bf16(a, b, c, 0, 0, 0);
}
__device__ __forceinline__ f32x16 mfma32(short8 a, short8 b, f32x16 c) {
  return __builtin_amdgcn_mfma_f32_32x32x16_bf16(a, b, c, 0, 0, 0);
}

// pack 8 f32 P-values into one PV B-frag (k-slice), R3-proven mapping:
//   lower lane: {own w0, own w1, partner w0, partner w1}
//   upper lane: {partner w2, partner w3, own w2, own w3}
__device__ __forceinline__ short8 pack_frag(u32 w0, u32 w1, u32 w2, u32 w3, bool hi) {
  u32 x0 = (u32)__shfl_xor((int)w0, 32), x1 = (u32)__shfl_xor((int)w1, 32);
  u32 x2 = (u32)__shfl_xor((int)w2, 32), x3 = (u32)__shfl_xor((int)w3, 32);
  u32x4 f = { hi ? x2 : w0, hi ? x3 : w1, hi ? w2 : x0, hi ? w3 : x1 };
  return __builtin_bit_cast(short8, f);
}

// ---------------- conversion / transpose kernels ----------------

__global__ void k_conv_x(const float* __restrict__ x, u16* __restrict__ xb, int n) {
  int i = blockIdx.x * 256 + threadIdx.x;
  if (i < n) xb[i] = f2bf(x[i]);
}

__global__ __launch_bounds__(256) void k_transpose_w(const float* __restrict__ w,
                                                     u16* __restrict__ wt,
                                                     int rows, int cols) {
  __shared__ float tile[32][33];
  int tx = threadIdx.x & 31, ty = threadIdx.x >> 5;
  int kb = blockIdx.x * 32;
  int nb = blockIdx.y * 32;
#pragma unroll
  for (int j = 0; j < 4; j++)
    tile[ty + 8 * j][tx] = w[(size_t)(kb + ty + 8 * j) * cols + nb + tx];
  __syncthreads();
#pragma unroll
  for (int j = 0; j < 4; j++)
    wt[(size_t)(nb + ty + 8 * j) * rows + kb + tx] = f2bf(tile[tx][ty + 8 * j]);
}

// ---------------- QKV GEMM + bias + RoPE epilogue ----------------
__global__ __launch_bounds__(256) void k_qkv(const u16* __restrict__ A,
                                             const u16* __restrict__ Bt,
                                             const float* __restrict__ bias,
                                             u16* __restrict__ Qb,
                                             u16* __restrict__ Kb,
                                             u16* __restrict__ Vt) {
  __shared__ u16 As[128][40];
  __shared__ u16 Bs[128][40];
  int t = threadIdx.x;
  int w = t >> 6, lane = t & 63, g = lane >> 4, c = lane & 15;
  int wr = w >> 1, wc = w & 1;
  int bm = blockIdx.x * 128, bn = blockIdx.y * 128;

  f32x4 acc[4][4];
#pragma unroll
  for (int m = 0; m < 4; m++)
#pragma unroll
    for (int n = 0; n < 4; n++) acc[m][n] = (f32x4){0.f, 0.f, 0.f, 0.f};

  int srow = t >> 1, sseg = (t & 1) * 16;
  for (int bk = 0; bk < EMB; bk += 32) {
    const u16* ga = A  + (size_t)(bm + srow) * EMB + bk + sseg;
    const u16* gb = Bt + (size_t)(bn + srow) * EMB + bk + sseg;
    short8 a0 = *(const short8*)ga, a1 = *(const short8*)(ga + 8);
    short8 b0 = *(const short8*)gb, b1 = *(const short8*)(gb + 8);
    __syncthreads();
    *(short8*)&As[srow][sseg] = a0; *(short8*)&As[srow][sseg + 8] = a1;
    *(short8*)&Bs[srow][sseg] = b0; *(short8*)&Bs[srow][sseg + 8] = b1;
    __syncthreads();
    short8 af[4], bf[4];
#pragma unroll
    for (int m = 0; m < 4; m++) af[m] = *(const short8*)&As[wr * 64 + m * 16 + c][g * 8];
#pragma unroll
    for (int n = 0; n < 4; n++) bf[n] = *(const short8*)&Bs[wc * 64 + n * 16 + c][g * 8];
#pragma unroll
    for (int m = 0; m < 4; m++)
#pragma unroll
      for (int n = 0; n < 4; n++) acc[m][n] = mfma16(af[m], bf[n], acc[m][n]);
  }

  int colbase = bn + wc * 64;
  int sec = colbase / EMB;               // 0=Q 1=K 2=V
  int hh  = (colbase % EMB) / DH;
  float qs = (sec == 0) ? QSCALE : 1.0f;
  float invf[2];
#pragma unroll
  for (int n = 0; n < 2; n++) {
    int d1 = n * 16 + c;
    invf[n] = exp2f(-(float)d1 * (13.287712379549449f / 32.0f));
  }
#pragma unroll
  for (int m = 0; m < 4; m++) {
    int rowb = bm + wr * 64 + m * 16 + 4 * g;
#pragma unroll
    for (int e = 0; e < 4; e++) {
      int srw = rowb + e;
      float v[4];
#pragma unroll
      for (int n = 0; n < 4; n++) v[n] = acc[m][n][e] + bias[colbase + n * 16 + c];
      if (sec == 2) {
#pragma unroll
        for (int n = 0; n < 4; n++)
          Vt[(size_t)(hh * DH + n * 16 + c) * S_LEN + srw] = f2bf(v[n]);
      } else {
        u16* dst = (sec == 0) ? Qb : Kb;
        size_t base = ((size_t)hh * S_LEN + srw) * DH;
#pragma unroll
        for (int n = 0; n < 2; n++) {
          int d1 = n * 16 + c;
          float ang = (float)srw * invf[n];
          float sn, cs;
          sincosf(ang, &sn, &cs);
          float o1 = (v[n] * cs - v[n + 2] * sn) * qs;
          float o2 = (v[n + 2] * cs + v[n] * sn) * qs;
          dst[base + d1]      = f2bf(o1);
          dst[base + d1 + 32] = f2bf(o2);
        }
      }
    }
  }
}

// ---------------- flash attention ----------------
// Swapped-operand, LDS-free tiles; 4-wave KV split per 32-row Q block.
// Register-pipelined KV loop: tile i+1's K/V loads issue before tile i's
// compute, hiding L2/L3 latency under softmax+MFMA (T14 pattern).

struct KVt { short8 k0, k1, k2, k3, v0, v1, v2, v3; };

__device__ __forceinline__ KVt load_kv(int kv0, int qi, int half,
                                       const u16* __restrict__ Kh,
                                       const u16* __restrict__ Vh) {
  KVt r;
  const u16* kp = Kh + (size_t)(kv0 + qi) * DH + half * 8;
  r.k0 = *(const short8*)(kp);
  r.k1 = *(const short8*)(kp + 16);
  r.k2 = *(const short8*)(kp + 32);
  r.k3 = *(const short8*)(kp + 48);
  const u16* vp = Vh + (size_t)qi * S_LEN + kv0 + half * 8;
  r.v0 = *(const short8*)(vp);
  r.v1 = *(const short8*)(vp + 16);
  r.v2 = *(const short8*)(vp + (size_t)32 * S_LEN);
  r.v3 = *(const short8*)(vp + (size_t)32 * S_LEN + 16);
  return r;
}

__device__ __forceinline__ void attn_compute(const KVt& t, bool masked, int qi, int half,
    short8 qf0, short8 qf1, short8 qf2, short8 qf3,
    f32x16& acc0, f32x16& acc1, float& m, float& l) {
  __builtin_amdgcn_s_setprio(1);
  f32x16 sc = {0,0,0,0,0,0,0,0,0,0,0,0,0,0,0,0};
  sc = mfma32(t.k0, qf0, sc);
  sc = mfma32(t.k1, qf1, sc);
  sc = mfma32(t.k2, qf2, sc);
  sc = mfma32(t.k3, qf3, sc);
  __builtin_amdgcn_s_setprio(0);
  if (masked) {
#pragma unroll
    for (int i = 0; i < 16; i++) {
      int kl = (i & 3) + 8 * (i >> 2) + 4 * half;
      if (kl > qi) sc[i] = -1e30f;
    }
  }
  float t0 = fmaxf(fmaxf(sc[0], sc[1]), fmaxf(sc[2], sc[3]));
  float t1 = fmaxf(fmaxf(sc[4], sc[5]), fmaxf(sc[6], sc[7]));
  float t2 = fmaxf(fmaxf(sc[8], sc[9]), fmaxf(sc[10], sc[11]));
  float t3 = fmaxf(fmaxf(sc[12], sc[13]), fmaxf(sc[14], sc[15]));
  float rmax = pr_max(fmaxf(fmaxf(t0, t1), fmaxf(t2, t3)));
  if (__any(rmax > m + 8.0f)) {
    float mn = fmaxf(m, rmax);
    float f = fexp2(m - mn);
    m = mn; l *= f;
#pragma unroll
    for (int i = 0; i < 16; i++) { acc0[i] *= f; acc1[i] *= f; }
  }
  f32x16 p;
#pragma unroll
  for (int i = 0; i < 16; i++) p[i] = fexp2(sc[i] - m);
  l += ((p[0] + p[1]) + (p[2] + p[3])) + ((p[4] + p[5]) + (p[6] + p[7]))
     + ((p[8] + p[9]) + (p[10] + p[11])) + ((p[12] + p[13]) + (p[14] + p[15]));
  bool hi = (half != 0);
  short8 pa0 = pack_frag(cvtpk(p[0], p[1]),   cvtpk(p[2], p[3]),
                         cvtpk(p[4], p[5]),   cvtpk(p[6], p[7]), hi);
  short8 pa1 = pack_frag(cvtpk(p[8], p[9]),   cvtpk(p[10], p[11]),
                         cvtpk(p[12], p[13]), cvtpk(p[14], p[15]), hi);
  __builtin_amdgcn_s_setprio(1);
  acc0 = mfma32(t.v0, pa0, acc0);
  acc0 = mfma32(t.v1, pa1, acc0);
  acc1 = mfma32(t.v2, pa0, acc1);
  acc1 = mfma32(t.v3, pa1, acc1);
  __builtin_amdgcn_s_setprio(0);
}

__global__ __launch_bounds__(256, 4) void k_attn(const u16* __restrict__ Q,
                                                 const u16* __restrict__ K,
                                                 const u16* __restrict__ Vt,
                                                 u16* __restrict__ O) {
  __shared__ float Lacc[3][64][33];
  __shared__ float Lml[2][3][32];

  int t = threadIdx.x;
  int w = t >> 6, lane = t & 63;
  int qi = lane & 31, half = lane >> 5;
  int b = blockIdx.x;
  int h = b % NH;
  int qb = 127 - b / NH;              // longest blocks first

  const u16* Qh = Q  + (size_t)h * S_LEN * DH;
  const u16* Kh = K  + (size_t)h * S_LEN * DH;
  const u16* Vh = Vt + (size_t)h * DH * S_LEN;

  const u16* qp = Qh + (size_t)(qb * 32 + qi) * DH + half * 8;
  short8 qf0 = *(const short8*)(qp);
  short8 qf1 = *(const short8*)(qp + 16);
  short8 qf2 = *(const short8*)(qp + 32);
  short8 qf3 = *(const short8*)(qp + 48);

  f32x16 acc0 = {0,0,0,0,0,0,0,0,0,0,0,0,0,0,0,0};
  f32x16 acc1 = {0,0,0,0,0,0,0,0,0,0,0,0,0,0,0,0};
  float m = -1e30f, l = 0.f;

  int nt = qb + 1;                     // total KV tiles (last one masked)
  int ck = (nt + 3) >> 2;              // tiles per wave
  int start = w * ck;
  int end   = min(start + ck, nt);

  if (start < end) {
    KVt cur = load_kv(start * 32, qi, half, Kh, Vh);
#pragma unroll 2
    for (int tt = start; tt < end; tt++) {
      KVt nxt;
      if (tt + 1 < end) nxt = load_kv((tt + 1) * 32, qi, half, Kh, Vh);
      attn_compute(cur, tt == nt - 1, qi, half, qf0, qf1, qf2, qf3,
                   acc0, acc1, m, l);
      cur = nxt;
    }
  }

  // cross-wave merge
  float l2 = pr_add(l);
  if (w > 0) {
#pragma unroll
    for (int i = 0; i < 16; i++) {
      Lacc[w - 1][lane][i]      = acc0[i];
      Lacc[w - 1][lane][16 + i] = acc1[i];
    }
    if (half == 0) { Lml[0][w - 1][qi] = m; Lml[1][w - 1][qi] = l2; }
  }
  __syncthreads();
  if (w == 0) {
    float mw[3], lw[3];
    float M = m;
#pragma unroll
    for (int j = 0; j < 3; j++) { mw[j] = Lml[0][j][qi]; lw[j] = Lml[1][j][qi]; M = fmaxf(M, mw[j]); }
    float f0 = fexp2(m - M);
    float ltot = l2 * f0;
#pragma unroll
    for (int i = 0; i < 16; i++) { acc0[i] *= f0; acc1[i] *= f0; }
#pragma unroll
    for (int j = 0; j < 3; j++) {
      float fj = fexp2(mw[j] - M);
      ltot += lw[j] * fj;
#pragma unroll
      for (int i = 0; i < 16; i++) {
        acc0[i] += fj * Lacc[j][lane][i];
        acc1[i] += fj * Lacc[j][lane][16 + i];
      }
    }
    float rl = 1.0f / ltot;
    u16* orow = O + (size_t)(qb * 32 + qi) * EMB + h * DH;
#pragma unroll
    for (int i = 0; i < 16; i += 2) {
      int dl = (i & 3) + 8 * (i >> 2) + 4 * half;
      u32 wa = cvtpk(acc0[i] * rl, acc0[i + 1] * rl);
      u32 wb = cvtpk(acc1[i] * rl, acc1[i + 1] * rl);
      *(u32*)(orow + dl)      = wa;
      *(u32*)(orow + 32 + dl) = wb;
    }
  }
}

// ---------------- output projection ----------------
__global__ __launch_bounds__(256) void k_out(const u16* __restrict__ A,
                                             const u16* __restrict__ Bt,
                                             const float* __restrict__ bias,
                                             float* __restrict__ out) {
  __shared__ u16 As[128][40];
  __shared__ u16 Bs[128][40];
  int t = threadIdx.x;
  int w = t >> 6, lane = t & 63, g = lane >> 4, c = lane & 15;
  int wr = w >> 1, wc = w & 1;
  int bm = blockIdx.x * 128, bn = blockIdx.y * 128;

  f32x4 acc[4][4];
#pragma unroll
  for (int m = 0; m < 4; m++)
#pragma unroll
    for (int n = 0; n < 4; n++) acc[m][n] = (f32x4){0.f, 0.f, 0.f, 0.f};

  int srow = t >> 1, sseg = (t & 1) * 16;
  for (int bk = 0; bk < EMB; bk += 32) {
    const u16* ga = A  + (size_t)(bm + srow) * EMB + bk + sseg;
    const u16* gb = Bt + (size_t)(bn + srow) * EMB + bk + sseg;
    short8 a0 = *(const short8*)ga, a1 = *(const short8*)(ga + 8);
    short8 b0 = *(const short8*)gb, b1 = *(const short8*)(gb + 8);
    __syncthreads();
    *(short8*)&As[srow][sseg] = a0; *(short8*)&As[srow][sseg + 8] = a1;
    *(short8*)&Bs[srow][sseg] = b0; *(short8*)&Bs[srow][sseg + 8] = b1;
    __syncthreads();
    short8 af[4], bf[4];
#pragma unroll
    for (int m = 0; m < 4; m++) af[m] = *(const short8*)&As[wr * 64 + m * 16 + c][g * 8];
#pragma unroll
    for (int n = 0; n < 4; n++) bf[n] = *(const short8*)&Bs[wc * 64 + n * 16 + c][g * 8];
#pragma unroll
    for (int m = 0; m < 4; m++)
#pragma unroll
      for (int n = 0; n < 4; n++) acc[m][n] = mfma16(af[m], bf[n], acc[m][n]);
  }
  int colbase = bn + wc * 64;
#pragma unroll
  for (int m = 0; m < 4; m++) {
    int rowb = bm + wr * 64 + m * 16 + 4 * g;
#pragma unroll
    for (int e = 0; e < 4; e++) {
      int srw = rowb + e;
#pragma unroll
      for (int n = 0; n < 4; n++) {
        int col = colbase + n * 16 + c;
        out[(size_t)srw * EMB + col] = acc[m][n][e] + bias[col];
      }
    }
  }
}

// ---------------- launcher ----------------

extern "C" void kernel_launch(void* const* d_in, const int* in_sizes, int n_in,
                              void* d_out, int out_size, void* d_ws, size_t ws_size,
                              hipStream_t stream) {
  const float* x    = (const float*)d_in[0];
  const float* Wqkv = (const float*)d_in[2];
  const float* bqkv = (const float*)d_in[3];
  const float* Wout = (const float*)d_in[4];
  const float* bout = (const float*)d_in[5];
  float* out = (float*)d_out;

  char* ws = (char*)d_ws;
  u16* xb     = (u16*)(ws);
  u16* wqkvt  = (u16*)(ws + 6291456);
  u16* woutt  = (u16*)(ws + 9830400);
  u16* Qb     = (u16*)(ws + 11010048);
  u16* Kb     = (u16*)(ws + 17301504);
  u16* Vtb    = (u16*)(ws + 23592960);
  u16* Ob     = (u16*)(ws + 29884416);

  k_conv_x<<<(S_LEN * EMB + 255) / 256, 256, 0, stream>>>(x, xb, S_LEN * EMB);
  k_transpose_w<<<dim3(EMB / 32, 3 * EMB / 32), 256, 0, stream>>>(Wqkv, wqkvt, EMB, 3 * EMB);
  k_transpose_w<<<dim3(EMB / 32, EMB / 32), 256, 0, stream>>>(Wout, woutt, EMB, EMB);

  k_qkv<<<dim3(32, 18), 256, 0, stream>>>(xb, wqkvt, bqkv, Qb, Kb, Vtb);
  k_attn<<<NH * 128, 256, 0, stream>>>(Qb, Kb, Vtb, Ob);
  k_out<<<dim3(32, 6), 256, 0, stream>>>(Ob, woutt, bout, out);
}